// Round 16
// baseline (86.878 us; speedup 1.0000x reference)
//
#include <hip/hip_runtime.h>
#include <math.h>

#define H_DIM  4096
#define NE     64
#define TOPK   8
#define KHALF  2048               // K per split
#define WTERM  (NE * H_DIM)       // 262144 elems per packed-W term plane
#define LO_SCALE 2048.0f          // 2^11
#define INV_LO_SCALE (1.0f / 2048.0f)

using f16x8  = __attribute__((ext_vector_type(8))) _Float16;
using hp16x2 = __attribute__((ext_vector_type(2))) __fp16;   // cvt_pkrtz return type
using f32x4  = __attribute__((ext_vector_type(4))) float;

// ---------------- W pre-pack: fp16 2-term split in MFMA B-fragment order ----
// pk[term][kstep][nf][lane][8]: lane = g*16 + (e&15), slot j -> k = kstep*32 + g*8 + j
__global__ __launch_bounds__(256, 1)
void pack_w_kernel(const float* __restrict__ W, _Float16* __restrict__ pk)
{
    int id = blockIdx.x * 256 + threadIdx.x;          // 0 .. 262143
    int e = id >> 12;                                  // / 4096
    int k = id & 4095;
    float f = W[id];
    _Float16 h = (_Float16)f;                          // RNE
    float r = (f - (float)h) * LO_SCALE;               // exact residual, scaled to fp16-normal range
    _Float16 l = (_Float16)r;
    int nf = e >> 4, rr = e & 15;
    int kstep = k >> 5, g = (k >> 3) & 3, j = k & 7;
    int lane = g * 16 + rr;
    size_t idx = (size_t)(kstep * 4 + nf) * 512 + (size_t)lane * 8 + j;
    pk[idx] = h;
    pk[WTERM + idx] = l;
}

// ---------------- main GEMM: partial[kh] = x[:, kh*2048 : +2048] . W^T ------
// (champion 72.9 µs structure; ONLY change: x loads are non-temporal so the
// use-once 256MB x stream doesn't evict the hot 1MB pk from L2.)
// block = 4 waves x 16 tokens (64 tokens), one K half; W k-slice shared via LDS;
// x staged coalesced -> transposed pad-17 LDS (per-wave private).
// 32 phases x 2 ksteps; raw s_barrier + lgkmcnt(0); counted vmcnt only.
__global__ __launch_bounds__(256, 2)
void moe_logits_mfma(const float* __restrict__ x, const _Float16* __restrict__ pk,
                     float* __restrict__ part0, float* __restrict__ part1)
{
    const int lane = threadIdx.x & 63;
    const int wid  = threadIdx.x >> 6;          // 0..3 token sub-group / stage quarter
    const int kh   = blockIdx.x & 1;            // K half
    const int tg   = blockIdx.x >> 1;           // 0..255 token group of 64
    const int row0 = tg * 64 + wid * 16;
    const int g = lane >> 4, r = lane & 15;

    // coalesced x staging base: instr i covers rows i*4+(lane>>4), 16B at col (lane&15)*4
    const float* xg = x + (size_t)(row0 + (lane >> 4)) * H_DIM + kh * KHALF + (lane & 15) * 4;
    // W staging source: this wave's quarter of each per-kstep slice
    const _Float16* wq = pk + (size_t)(kh * 64) * 2048 + wid * 512 + (size_t)lane * 8;

    __shared__ _Float16 sw[2][2][4096];   // [buf][kip][t*2048+nf*512+lane*8] : 32 KB
    __shared__ float    sx[2][4][1088];   // [buf][wave][col*17 + row]        : 34.8 KB
    const int lbase = wid * 512 + lane * 8;
    const int c0 = (lane & 15) * 4;       // staged col group
    const int rq = lane >> 4;             // staged row-in-quad

    f32x4 acc[4], accL[4];
#pragma unroll
    for (int nf = 0; nf < 4; ++nf) { acc[nf] = (f32x4)0.0f; accL[nf] = (f32x4)0.0f; }

    f32x4 xst[2][4];       // [phase-buf][row-quad]
    f16x8 wr[2][2][2];     // [phase-buf][kip][term]  W for phase P+1 in wr[(P+1)&1]

    // ---- prologue: regs <- x/W of phases 0,1; LDS buf0 <- phase 0
#pragma unroll
    for (int i = 0; i < 4; ++i) {
        xst[0][i] = __builtin_nontemporal_load(
                        (const f32x4*)(xg + (size_t)i * 4 * H_DIM));
        xst[1][i] = __builtin_nontemporal_load(
                        (const f32x4*)(xg + (size_t)i * 4 * H_DIM + 64));
    }
#pragma unroll
    for (int kip = 0; kip < 2; ++kip)
#pragma unroll
        for (int t = 0; t < 2; ++t) {
            wr[0][kip][t] = *(const f16x8*)(wq + kip * 2048 + t * WTERM);
            wr[1][kip][t] = *(const f16x8*)(wq + 4096 + kip * 2048 + t * WTERM);
        }
#pragma unroll
    for (int kip = 0; kip < 2; ++kip)
#pragma unroll
        for (int t = 0; t < 2; ++t)
            *(f16x8*)&sw[0][kip][t * 2048 + lbase] = wr[0][kip][t];
#pragma unroll
    for (int i = 0; i < 4; ++i)
#pragma unroll
        for (int j = 0; j < 4; ++j)
            sx[0][wid][(c0 + j) * 17 + i * 4 + rq] = xst[0][i][j];
    asm volatile("s_waitcnt lgkmcnt(0)\n\ts_barrier" ::: "memory");

    // PHASE(b_, DSW_, PFW_, PFX_):
    //  b_: phase parity (LDS/reg buffer), DSW_: ds_write regs of P+1 -> buf b^1
    //  PFW_: issue W(P+2) -> wr[b_];  PFX_: issue x(P+2) -> xst[b_]
#define PHASE(b_, DSW_, PFW_, PFX_)                                            \
    do {                                                                       \
        if (DSW_) {                                                            \
            _Pragma("unroll")                                                  \
            for (int kip = 0; kip < 2; ++kip)                                  \
                _Pragma("unroll")                                              \
                for (int t = 0; t < 2; ++t)                                    \
                    *(f16x8*)&sw[(b_) ^ 1][kip][t * 2048 + lbase] =            \
                        wr[(b_) ^ 1][kip][t];                                  \
            _Pragma("unroll")                                                  \
            for (int i = 0; i < 4; ++i)                                        \
                _Pragma("unroll")                                              \
                for (int j = 0; j < 4; ++j)                                    \
                    sx[(b_) ^ 1][wid][(c0 + j) * 17 + i * 4 + rq] =            \
                        xst[(b_) ^ 1][i][j];                                   \
        }                                                                      \
        if (PFW_) {                                                            \
            _Pragma("unroll")                                                  \
            for (int kip = 0; kip < 2; ++kip)                                  \
                _Pragma("unroll")                                              \
                for (int t = 0; t < 2; ++t)                                    \
                    wr[b_][kip][t] = *(const f16x8*)(wq + (b_) * 4096 + 8192   \
                                                     + kip * 2048 + t * WTERM);\
        }                                                                      \
        if (PFX_) {                                                            \
            _Pragma("unroll")                                                  \
            for (int i = 0; i < 4; ++i)                                        \
                xst[b_][i] = __builtin_nontemporal_load(                       \
                    (const f32x4*)(xg + (size_t)i * 4 * H_DIM                  \
                                   + (b_) * 64 + 128));                        \
        }                                                                      \
        _Pragma("unroll")                                                      \
        for (int kip = 0; kip < 2; ++kip) {                                    \
            f16x8 wa[2][4];                                                    \
            _Pragma("unroll")                                                  \
            for (int t = 0; t < 2; ++t)                                        \
                _Pragma("unroll")                                              \
                for (int nf = 0; nf < 4; ++nf)                                 \
                    wa[t][nf] = *(const f16x8*)                                \
                        &sw[b_][kip][t * 2048 + nf * 512 + lane * 8];          \
            float xv[8];                                                       \
            _Pragma("unroll")                                                  \
            for (int j = 0; j < 8; ++j)                                        \
                xv[j] = sx[b_][wid][(kip * 32 + g * 8 + j) * 17 + r];          \
            f16x8 a1, a2;                                                      \
            _Pragma("unroll")                                                  \
            for (int j = 0; j < 8; j += 2) {                                   \
                float v0 = xv[j], v1 = xv[j + 1];                              \
                hp16x2 hp = __builtin_amdgcn_cvt_pkrtz(v0, v1);                \
                float r0 = (v0 - (float)hp[0]) * LO_SCALE;                     \
                float r1 = (v1 - (float)hp[1]) * LO_SCALE;                     \
                hp16x2 lp = __builtin_amdgcn_cvt_pkrtz(r0, r1);                \
                a1[j]     = (_Float16)hp[0];                                   \
                a1[j + 1] = (_Float16)hp[1];                                   \
                a2[j]     = (_Float16)lp[0];                                   \
                a2[j + 1] = (_Float16)lp[1];                                   \
            }                                                                  \
            _Pragma("unroll")                                                  \
            for (int nf = 0; nf < 4; ++nf) {                                   \
                acc[nf]  = __builtin_amdgcn_mfma_f32_16x16x32_f16(             \
                               a1, wa[0][nf], acc[nf], 0, 0, 0);               \
                accL[nf] = __builtin_amdgcn_mfma_f32_16x16x32_f16(             \
                               a1, wa[1][nf], accL[nf], 0, 0, 0);              \
                accL[nf] = __builtin_amdgcn_mfma_f32_16x16x32_f16(             \
                               a2, wa[0][nf], accL[nf], 0, 0, 0);              \
            }                                                                  \
        }                                                                      \
        asm volatile("s_waitcnt lgkmcnt(0)\n\ts_barrier" ::: "memory");        \
    } while (0)

    // phases 0..29 (15 pairs), full pipeline
#pragma unroll 1
    for (int it = 0; it < 15; ++it) {
        PHASE(0, 1, 1, 1);
        PHASE(1, 1, 1, 1);
        xg += 128;
        wq += 8192;
    }
    // phase 30: stage phase-31 regs, no more prefetch
    PHASE(0, 1, 0, 0);
    // phase 31: compute only
    PHASE(1, 0, 0, 0);

#undef PHASE

    // store partial tile: D row (token) = g*4+q, col (expert) = nf*16+r
    float* outp = kh == 0 ? part0 : part1;
#pragma unroll
    for (int nf = 0; nf < 4; ++nf)
#pragma unroll
        for (int q = 0; q < 4; ++q) {
            float v = acc[nf][q] + accL[nf][q] * INV_LO_SCALE;
            outp[(size_t)(row0 + g * 4 + q) * NE + nf * 16 + r] = v;
        }
}

// ---------------- router: transposed, shuffle-free ---------------------------
// lane = token; all softmax + top-8 in registers (pure VALU, no cross-lane).
// scores aliases p0, logits aliases p1: each lane reads only its own row fully
// into regs before writing it; rows are lane-exclusive -> race-free.
__global__ __launch_bounds__(64, 1)
void router_kernel(const float* __restrict__ p0, const float* __restrict__ p1,
                   float* __restrict__ scores, float* __restrict__ logits,
                   float* __restrict__ wts, float* __restrict__ inds)
{
    const int token = blockIdx.x * 64 + threadIdx.x;
    const float* r0 = p0 + (size_t)token * NE;
    const float* r1 = p1 + (size_t)token * NE;

    // load + sum partials into 64 regs
    f32x4 l[16];
#pragma unroll
    for (int i = 0; i < 16; ++i) {
        f32x4 a = *(const f32x4*)(r0 + i * 4);
        f32x4 b = *(const f32x4*)(r1 + i * 4);
        l[i] = a + b;
    }
    // write logits
    float* lo = logits + (size_t)token * NE;
#pragma unroll
    for (int i = 0; i < 16; ++i)
        *(f32x4*)(lo + i * 4) = l[i];

    // softmax max
    float m = l[0][0];
#pragma unroll
    for (int i = 0; i < 16; ++i)
        m = fmaxf(m, fmaxf(fmaxf(l[i][0], l[i][1]), fmaxf(l[i][2], l[i][3])));

    // p = exp(l - m) in place; s = sum
    float s = 0.0f;
#pragma unroll
    for (int i = 0; i < 16; ++i) {
#pragma unroll
        for (int j = 0; j < 4; ++j) {
            float p = expf(l[i][j] - m);
            l[i][j] = p;
            s += p;
        }
    }
    // write scores = p * (1/s)  (order-preserving scale)
    const float invs = 1.0f / s;
    float* so = scores + (size_t)token * NE;
#pragma unroll
    for (int i = 0; i < 16; ++i) {
        f32x4 v = l[i] * invs;
        *(f32x4*)(so + i * 4) = v;
    }

    // destructive top-8 extraction on p (selection order == scores order).
    // First-match scan with (idx<0) guard: stable, lower-index tie-break.
    float tv[TOPK];
    int   ti[TOPK];
    float sum8 = 0.0f;
#pragma unroll
    for (int k = 0; k < TOPK; ++k) {
        float m2 = l[0][0];
#pragma unroll
        for (int i = 0; i < 16; ++i)
            m2 = fmaxf(m2, fmaxf(fmaxf(l[i][0], l[i][1]), fmaxf(l[i][2], l[i][3])));
        int idx = -1;
#pragma unroll
        for (int i = 0; i < 16; ++i) {
#pragma unroll
            for (int j = 0; j < 4; ++j) {
                bool take = (idx < 0) && (l[i][j] == m2);
                idx = take ? (i * 4 + j) : idx;
                l[i][j] = take ? -1.0f : l[i][j];   // p > 0, never re-selected
            }
        }
        tv[k] = m2; ti[k] = idx;
        sum8 += m2;
    }

    // weights: p_k / sum(p_top8)  == ref's L1-renorm of scores exactly
    const float inv8 = 1.0f / sum8;
    float* wo = wts  + (size_t)token * TOPK;
    float* io = inds + (size_t)token * TOPK;
#pragma unroll
    for (int h = 0; h < 2; ++h) {
        f32x4 wv, iv;
#pragma unroll
        for (int j = 0; j < 4; ++j) {
            wv[j] = tv[h * 4 + j] * inv8;
            iv[j] = (float)ti[h * 4 + j];
        }
        *(f32x4*)(wo + h * 4) = wv;
        *(f32x4*)(io + h * 4) = iv;
    }
}

extern "C" void kernel_launch(void* const* d_in, const int* in_sizes, int n_in,
                              void* d_out, int out_size, void* d_ws, size_t ws_size,
                              hipStream_t stream)
{
    const float* x = (const float*)d_in[0];
    const float* W = (const float*)d_in[1];
    const int N = in_sizes[0] / H_DIM;   // 16384

    float* out    = (float*)d_out;
    float* scores = out;                          // [N,64]  (doubles as partial kh=0)
    float* logits = out + (size_t)N * NE;         // [N,64]  (doubles as partial kh=1)
    float* wts    = out + (size_t)2 * N * NE;     // [N,8]
    float* inds   = wts + (size_t)N * TOPK;       // [N,8] as float

    _Float16* pk = (_Float16*)d_ws;               // 2 * 262144 * 2B = 1 MB

    pack_w_kernel<<<(NE * H_DIM) / 256, 256, 0, stream>>>(W, pk);
    moe_logits_mfma<<<(N / 64) * 2, 256, 0, stream>>>(x, pk, scores, logits);
    router_kernel<<<N / 64, 64, 0, stream>>>(scores, logits, scores, logits,
                                             wts, inds);
}

// Round 17
// 75.145 us; speedup vs baseline: 1.1561x; 1.1561x over previous
//
#include <hip/hip_runtime.h>
#include <math.h>

#define H_DIM  4096
#define NE     64
#define TOPK   8
#define KHALF  2048               // K per split
#define WTERM  (NE * H_DIM)       // 262144 elems per packed-W term plane
#define LO_SCALE 2048.0f          // 2^11
#define INV_LO_SCALE (1.0f / 2048.0f)

using f16x8  = __attribute__((ext_vector_type(8))) _Float16;
using hp16x2 = __attribute__((ext_vector_type(2))) __fp16;   // cvt_pkrtz return type
using f32x4  = __attribute__((ext_vector_type(4))) float;

// ---------------- W pre-pack: fp16 2-term split in MFMA B-fragment order ----
// pk[term][kstep][nf][lane][8]: lane = g*16 + (e&15), slot j -> k = kstep*32 + g*8 + j
__global__ __launch_bounds__(256, 1)
void pack_w_kernel(const float* __restrict__ W, _Float16* __restrict__ pk)
{
    int id = blockIdx.x * 256 + threadIdx.x;          // 0 .. 262143
    int e = id >> 12;                                  // / 4096
    int k = id & 4095;
    float f = W[id];
    _Float16 h = (_Float16)f;                          // RNE
    float r = (f - (float)h) * LO_SCALE;               // exact residual, scaled to fp16-normal range
    _Float16 l = (_Float16)r;
    int nf = e >> 4, rr = e & 15;
    int kstep = k >> 5, g = (k >> 3) & 3, j = k & 7;
    int lane = g * 16 + rr;
    size_t idx = (size_t)(kstep * 4 + nf) * 512 + (size_t)lane * 8 + j;
    pk[idx] = h;
    pk[WTERM + idx] = l;
}

// ---------------- main GEMM: partial[kh] = x[:, kh*2048 : +2048] . W^T ------
// (72.9 µs champion structure, verbatim)
// block = 4 waves x 16 tokens (64 tokens), one K half; W k-slice shared via LDS;
// x staged coalesced -> transposed pad-17 LDS (per-wave private).
// 32 phases x 2 ksteps; raw s_barrier + lgkmcnt(0); counted vmcnt only.
__global__ __launch_bounds__(256, 2)
void moe_logits_mfma(const float* __restrict__ x, const _Float16* __restrict__ pk,
                     float* __restrict__ part0, float* __restrict__ part1)
{
    const int lane = threadIdx.x & 63;
    const int wid  = threadIdx.x >> 6;          // 0..3 token sub-group / stage quarter
    const int kh   = blockIdx.x & 1;            // K half
    const int tg   = blockIdx.x >> 1;           // 0..255 token group of 64
    const int row0 = tg * 64 + wid * 16;
    const int g = lane >> 4, r = lane & 15;

    // coalesced x staging base: instr i covers rows i*4+(lane>>4), 16B at col (lane&15)*4
    const float* xg = x + (size_t)(row0 + (lane >> 4)) * H_DIM + kh * KHALF + (lane & 15) * 4;
    // W staging source: this wave's quarter of each per-kstep slice
    const _Float16* wq = pk + (size_t)(kh * 64) * 2048 + wid * 512 + (size_t)lane * 8;

    __shared__ _Float16 sw[2][2][4096];   // [buf][kip][t*2048+nf*512+lane*8] : 32 KB
    __shared__ float    sx[2][4][1088];   // [buf][wave][col*17 + row]        : 34.8 KB
    const int lbase = wid * 512 + lane * 8;
    const int c0 = (lane & 15) * 4;       // staged col group
    const int rq = lane >> 4;             // staged row-in-quad

    f32x4 acc[4], accL[4];
#pragma unroll
    for (int nf = 0; nf < 4; ++nf) { acc[nf] = (f32x4)0.0f; accL[nf] = (f32x4)0.0f; }

    f32x4 xst[2][4];       // [phase-buf][row-quad]
    f16x8 wr[2][2][2];     // [phase-buf][kip][term]  W for phase P+1 in wr[(P+1)&1]

    // ---- prologue: regs <- x/W of phases 0,1; LDS buf0 <- phase 0
#pragma unroll
    for (int i = 0; i < 4; ++i) {
        xst[0][i] = *(const f32x4*)(xg + (size_t)i * 4 * H_DIM);
        xst[1][i] = *(const f32x4*)(xg + (size_t)i * 4 * H_DIM + 64);
    }
#pragma unroll
    for (int kip = 0; kip < 2; ++kip)
#pragma unroll
        for (int t = 0; t < 2; ++t) {
            wr[0][kip][t] = *(const f16x8*)(wq + kip * 2048 + t * WTERM);
            wr[1][kip][t] = *(const f16x8*)(wq + 4096 + kip * 2048 + t * WTERM);
        }
#pragma unroll
    for (int kip = 0; kip < 2; ++kip)
#pragma unroll
        for (int t = 0; t < 2; ++t)
            *(f16x8*)&sw[0][kip][t * 2048 + lbase] = wr[0][kip][t];
#pragma unroll
    for (int i = 0; i < 4; ++i)
#pragma unroll
        for (int j = 0; j < 4; ++j)
            sx[0][wid][(c0 + j) * 17 + i * 4 + rq] = xst[0][i][j];
    asm volatile("s_waitcnt lgkmcnt(0)\n\ts_barrier" ::: "memory");

    // PHASE(b_, DSW_, PFW_, PFX_):
    //  b_: phase parity (LDS/reg buffer), DSW_: ds_write regs of P+1 -> buf b^1
    //  PFW_: issue W(P+2) -> wr[b_];  PFX_: issue x(P+2) -> xst[b_]
#define PHASE(b_, DSW_, PFW_, PFX_)                                            \
    do {                                                                       \
        if (DSW_) {                                                            \
            _Pragma("unroll")                                                  \
            for (int kip = 0; kip < 2; ++kip)                                  \
                _Pragma("unroll")                                              \
                for (int t = 0; t < 2; ++t)                                    \
                    *(f16x8*)&sw[(b_) ^ 1][kip][t * 2048 + lbase] =            \
                        wr[(b_) ^ 1][kip][t];                                  \
            _Pragma("unroll")                                                  \
            for (int i = 0; i < 4; ++i)                                        \
                _Pragma("unroll")                                              \
                for (int j = 0; j < 4; ++j)                                    \
                    sx[(b_) ^ 1][wid][(c0 + j) * 17 + i * 4 + rq] =            \
                        xst[(b_) ^ 1][i][j];                                   \
        }                                                                      \
        if (PFW_) {                                                            \
            _Pragma("unroll")                                                  \
            for (int kip = 0; kip < 2; ++kip)                                  \
                _Pragma("unroll")                                              \
                for (int t = 0; t < 2; ++t)                                    \
                    wr[b_][kip][t] = *(const f16x8*)(wq + (b_) * 4096 + 8192   \
                                                     + kip * 2048 + t * WTERM);\
        }                                                                      \
        if (PFX_) {                                                            \
            _Pragma("unroll")                                                  \
            for (int i = 0; i < 4; ++i)                                        \
                xst[b_][i] = *(const f32x4*)(xg + (size_t)i * 4 * H_DIM        \
                                             + (b_) * 64 + 128);               \
        }                                                                      \
        _Pragma("unroll")                                                      \
        for (int kip = 0; kip < 2; ++kip) {                                    \
            f16x8 wa[2][4];                                                    \
            _Pragma("unroll")                                                  \
            for (int t = 0; t < 2; ++t)                                        \
                _Pragma("unroll")                                              \
                for (int nf = 0; nf < 4; ++nf)                                 \
                    wa[t][nf] = *(const f16x8*)                                \
                        &sw[b_][kip][t * 2048 + nf * 512 + lane * 8];          \
            float xv[8];                                                       \
            _Pragma("unroll")                                                  \
            for (int j = 0; j < 8; ++j)                                        \
                xv[j] = sx[b_][wid][(kip * 32 + g * 8 + j) * 17 + r];          \
            f16x8 a1, a2;                                                      \
            _Pragma("unroll")                                                  \
            for (int j = 0; j < 8; j += 2) {                                   \
                float v0 = xv[j], v1 = xv[j + 1];                              \
                hp16x2 hp = __builtin_amdgcn_cvt_pkrtz(v0, v1);                \
                float r0 = (v0 - (float)hp[0]) * LO_SCALE;                     \
                float r1 = (v1 - (float)hp[1]) * LO_SCALE;                     \
                hp16x2 lp = __builtin_amdgcn_cvt_pkrtz(r0, r1);                \
                a1[j]     = (_Float16)hp[0];                                   \
                a1[j + 1] = (_Float16)hp[1];                                   \
                a2[j]     = (_Float16)lp[0];                                   \
                a2[j + 1] = (_Float16)lp[1];                                   \
            }                                                                  \
            _Pragma("unroll")                                                  \
            for (int nf = 0; nf < 4; ++nf) {                                   \
                acc[nf]  = __builtin_amdgcn_mfma_f32_16x16x32_f16(             \
                               a1, wa[0][nf], acc[nf], 0, 0, 0);               \
                accL[nf] = __builtin_amdgcn_mfma_f32_16x16x32_f16(             \
                               a1, wa[1][nf], accL[nf], 0, 0, 0);              \
                accL[nf] = __builtin_amdgcn_mfma_f32_16x16x32_f16(             \
                               a2, wa[0][nf], accL[nf], 0, 0, 0);              \
            }                                                                  \
        }                                                                      \
        asm volatile("s_waitcnt lgkmcnt(0)\n\ts_barrier" ::: "memory");        \
    } while (0)

    // phases 0..29 (15 pairs), full pipeline
#pragma unroll 1
    for (int it = 0; it < 15; ++it) {
        PHASE(0, 1, 1, 1);
        PHASE(1, 1, 1, 1);
        xg += 128;
        wq += 8192;
    }
    // phase 30: stage phase-31 regs, no more prefetch
    PHASE(0, 1, 0, 0);
    // phase 31: compute only
    PHASE(1, 0, 0, 0);

#undef PHASE

    // store partial tile: D row (token) = g*4+q, col (expert) = nf*16+r
    float* outp = kh == 0 ? part0 : part1;
#pragma unroll
    for (int nf = 0; nf < 4; ++nf)
#pragma unroll
        for (int q = 0; q < 4; ++q) {
            float v = acc[nf][q] + accL[nf][q] * INV_LO_SCALE;
            outp[(size_t)(row0 + g * 4 + q) * NE + nf * 16 + r] = v;
        }
}

// ---------------- router: transposed, shuffle-free ---------------------------
// lane = token; all softmax + top-8 in registers (pure VALU, no cross-lane).
// scores aliases p0, logits aliases p1: each lane reads only its own row fully
// into regs before writing it; rows are lane-exclusive -> race-free.
__global__ __launch_bounds__(64, 1)
void router_kernel(const float* __restrict__ p0, const float* __restrict__ p1,
                   float* __restrict__ scores, float* __restrict__ logits,
                   float* __restrict__ wts, float* __restrict__ inds)
{
    const int token = blockIdx.x * 64 + threadIdx.x;
    const float* r0 = p0 + (size_t)token * NE;
    const float* r1 = p1 + (size_t)token * NE;

    // load + sum partials into 64 regs
    f32x4 l[16];
#pragma unroll
    for (int i = 0; i < 16; ++i) {
        f32x4 a = *(const f32x4*)(r0 + i * 4);
        f32x4 b = *(const f32x4*)(r1 + i * 4);
        l[i] = a + b;
    }
    // write logits
    float* lo = logits + (size_t)token * NE;
#pragma unroll
    for (int i = 0; i < 16; ++i)
        *(f32x4*)(lo + i * 4) = l[i];

    // softmax max
    float m = l[0][0];
#pragma unroll
    for (int i = 0; i < 16; ++i)
        m = fmaxf(m, fmaxf(fmaxf(l[i][0], l[i][1]), fmaxf(l[i][2], l[i][3])));

    // p = exp(l - m) in place; s = sum
    float s = 0.0f;
#pragma unroll
    for (int i = 0; i < 16; ++i) {
#pragma unroll
        for (int j = 0; j < 4; ++j) {
            float p = expf(l[i][j] - m);
            l[i][j] = p;
            s += p;
        }
    }
    // write scores = p * (1/s)  (order-preserving scale)
    const float invs = 1.0f / s;
    float* so = scores + (size_t)token * NE;
#pragma unroll
    for (int i = 0; i < 16; ++i) {
        f32x4 v = l[i] * invs;
        *(f32x4*)(so + i * 4) = v;
    }

    // destructive top-8 extraction on p (selection order == scores order).
    // First-match scan with (idx<0) guard: stable, lower-index tie-break.
    float tv[TOPK];
    int   ti[TOPK];
    float sum8 = 0.0f;
#pragma unroll
    for (int k = 0; k < TOPK; ++k) {
        float m2 = l[0][0];
#pragma unroll
        for (int i = 0; i < 16; ++i)
            m2 = fmaxf(m2, fmaxf(fmaxf(l[i][0], l[i][1]), fmaxf(l[i][2], l[i][3])));
        int idx = -1;
#pragma unroll
        for (int i = 0; i < 16; ++i) {
#pragma unroll
            for (int j = 0; j < 4; ++j) {
                bool take = (idx < 0) && (l[i][j] == m2);
                idx = take ? (i * 4 + j) : idx;
                l[i][j] = take ? -1.0f : l[i][j];   // p > 0, never re-selected
            }
        }
        tv[k] = m2; ti[k] = idx;
        sum8 += m2;
    }

    // weights: p_k / sum(p_top8)  == ref's L1-renorm of scores exactly
    const float inv8 = 1.0f / sum8;
    float* wo = wts  + (size_t)token * TOPK;
    float* io = inds + (size_t)token * TOPK;
#pragma unroll
    for (int h = 0; h < 2; ++h) {
        f32x4 wv, iv;
#pragma unroll
        for (int j = 0; j < 4; ++j) {
            wv[j] = tv[h * 4 + j] * inv8;
            iv[j] = (float)ti[h * 4 + j];
        }
        *(f32x4*)(wo + h * 4) = wv;
        *(f32x4*)(io + h * 4) = iv;
    }
}

extern "C" void kernel_launch(void* const* d_in, const int* in_sizes, int n_in,
                              void* d_out, int out_size, void* d_ws, size_t ws_size,
                              hipStream_t stream)
{
    const float* x = (const float*)d_in[0];
    const float* W = (const float*)d_in[1];
    const int N = in_sizes[0] / H_DIM;   // 16384

    float* out    = (float*)d_out;
    float* scores = out;                          // [N,64]  (doubles as partial kh=0)
    float* logits = out + (size_t)N * NE;         // [N,64]  (doubles as partial kh=1)
    float* wts    = out + (size_t)2 * N * NE;     // [N,8]
    float* inds   = wts + (size_t)N * TOPK;       // [N,8] as float

    _Float16* pk = (_Float16*)d_ws;               // 2 * 262144 * 2B = 1 MB

    pack_w_kernel<<<(NE * H_DIM) / 256, 256, 0, stream>>>(W, pk);
    moe_logits_mfma<<<(N / 64) * 2, 256, 0, stream>>>(x, pk, scores, logits);
    router_kernel<<<N / 64, 64, 0, stream>>>(scores, logits, scores, logits,
                                             wts, inds);
}